// Round 2
// baseline (867.444 us; speedup 1.0000x reference)
//
#include <hip/hip_runtime.h>
#include <hip/hip_bf16.h>

#define NNODES 100000
#define NEDGES 1600000
#define NGRAPH 512
#define DIM    64
#define NLAYER 3
#define NBLK_SCAN 98   // ceil(100000/1024)

// ---------------- CSR build ----------------

__global__ void zero_kernel(int* __restrict__ deg, float* __restrict__ wdeg) {
    int i = blockIdx.x * 256 + threadIdx.x;
    if (i < NNODES) { deg[i] = 0; wdeg[i] = 0.f; }
}

__global__ void hist_kernel(const int* __restrict__ ei, const float* __restrict__ ea,
                            int* __restrict__ deg, float* __restrict__ wdeg) {
    int e = blockIdx.x * 256 + threadIdx.x;
    if (e >= NEDGES) return;
    int d = ei[NEDGES + e];
    atomicAdd(&deg[d], 1);
    atomicAdd(&wdeg[d], ea[e]);
}

__global__ __launch_bounds__(256) void scan_blocks_kernel(const int* __restrict__ deg,
                                                          int* __restrict__ row_ptr,
                                                          int* __restrict__ bsums) {
    __shared__ int sd[256];
    int tid = threadIdx.x;
    int base = blockIdx.x * 1024 + tid * 4;
    int v[4]; int local = 0;
    #pragma unroll
    for (int i = 0; i < 4; ++i) {
        int idx = base + i;
        int d = (idx < NNODES) ? deg[idx] : 0;
        v[i] = local; local += d;
    }
    sd[tid] = local;
    __syncthreads();
    for (int off = 1; off < 256; off <<= 1) {
        int t = (tid >= off) ? sd[tid - off] : 0;
        __syncthreads();
        sd[tid] += t;
        __syncthreads();
    }
    int excl = sd[tid] - local;
    #pragma unroll
    for (int i = 0; i < 4; ++i) {
        int idx = base + i;
        if (idx < NNODES) row_ptr[idx] = excl + v[i];
    }
    if (tid == 255) bsums[blockIdx.x] = sd[255];
}

__global__ __launch_bounds__(128) void scan_sums_kernel(int* __restrict__ bsums) {
    __shared__ int sd[128];
    int tid = threadIdx.x;
    int v = (tid < NBLK_SCAN) ? bsums[tid] : 0;
    sd[tid] = v;
    __syncthreads();
    for (int off = 1; off < 128; off <<= 1) {
        int t = (tid >= off) ? sd[tid - off] : 0;
        __syncthreads();
        sd[tid] += t;
        __syncthreads();
    }
    if (tid < NBLK_SCAN) bsums[tid] = sd[tid] - v;
}

__global__ void add_offsets_kernel(int* __restrict__ row_ptr, const int* __restrict__ bsums,
                                   int* __restrict__ cursor) {
    int i = blockIdx.x * 256 + threadIdx.x;
    if (i < NNODES) {
        int v = row_ptr[i] + bsums[i >> 10];
        row_ptr[i] = v;
        cursor[i] = v;
    }
    if (i == 0) row_ptr[NNODES] = NEDGES;
}

__global__ void scatter_kernel(const int* __restrict__ ei, const float* __restrict__ ea,
                               int* __restrict__ cursor, int* __restrict__ perm_src,
                               float* __restrict__ perm_e) {
    int e = blockIdx.x * 256 + threadIdx.x;
    if (e >= NEDGES) return;
    int s = ei[e], d = ei[NEDGES + e];
    int pos = atomicAdd(&cursor[d], 1);
    perm_src[pos] = s;
    perm_e[pos] = ea[e];
}

// ---------------- dense ----------------

__global__ void embed_kernel(const float* __restrict__ x,
                             const float* __restrict__ W,
                             const float* __restrict__ b,
                             float* __restrict__ h) {
    int gid = blockIdx.x * 256 + threadIdx.x;
    if (gid >= NNODES * 64) return;
    int n = gid >> 6, cch = gid & 63;
    float s = b[cch];
    #pragma unroll
    for (int k = 0; k < 4; ++k) s = fmaf(x[n * 4 + k], W[k * 64 + cch], s);
    h[gid] = s;
}

// a = h@W1 + b1 ; h <- h@W3 + b3 - wdeg*(h@W2)   (c written in-place into h;
// safe: each 8-row group is read+written only by its own lockstep wave, all
// reads precede all stores in program order)
__global__ __launch_bounds__(256) void gemm3_kernel(
    float* __restrict__ h, const float* __restrict__ wdeg,
    const float* __restrict__ W1, const float* __restrict__ b1,
    const float* __restrict__ W2,
    const float* __restrict__ W3, const float* __restrict__ b3,
    float* __restrict__ a) {
    __shared__ float w1s[4096], w2s[4096], w3s[4096];
    __shared__ float b1s[64], b3s[64];
    int tid = threadIdx.x;
    for (int i = tid; i < 4096; i += 256) {
        w1s[i] = W1[i]; w2s[i] = W2[i]; w3s[i] = W3[i];
    }
    if (tid < 64) { b1s[tid] = b1[tid]; b3s[tid] = b3[tid]; }
    __syncthreads();
    const int cch = tid & 63;
    const int sub = tid >> 6;
    int n0 = blockIdx.x * 32 + sub * 8;
    if (n0 >= NNODES) return;
    float acc1[8] = {0.f}, acc2[8] = {0.f}, acc3[8] = {0.f};
    float* hrow = h + (size_t)n0 * 64;
    #pragma unroll 4
    for (int k = 0; k < 64; ++k) {
        float w1v = w1s[k * 64 + cch];
        float w2v = w2s[k * 64 + cch];
        float w3v = w3s[k * 64 + cch];
        #pragma unroll
        for (int j = 0; j < 8; ++j) {
            float hv = hrow[j * 64 + k];
            acc1[j] = fmaf(hv, w1v, acc1[j]);
            acc2[j] = fmaf(hv, w2v, acc2[j]);
            acc3[j] = fmaf(hv, w3v, acc3[j]);
        }
    }
    #pragma unroll
    for (int j = 0; j < 8; ++j) {
        int n = n0 + j;
        a[(size_t)n * 64 + cch] = acc1[j] + b1s[cch];
        hrow[(size_t)j * 64 + cch] = acc3[j] + b3s[cch] - wdeg[n] * acc2[j];
    }
}

// h = relu(h + sum_{edges into node} e * a[src])  -- one wave per node, lane = channel
__global__ __launch_bounds__(256) void edge_agg_kernel(
    const float* __restrict__ a, float* __restrict__ h,
    const int* __restrict__ row_ptr, const int* __restrict__ perm_src,
    const float* __restrict__ perm_e) {
    int node = blockIdx.x * 4 + (threadIdx.x >> 6);
    if (node >= NNODES) return;
    int lane = threadIdx.x & 63;
    int start = row_ptr[node], end = row_ptr[node + 1];
    float acc = h[(size_t)node * 64 + lane];
    for (int b = start; b < end; b += 64) {
        int cnt = min(64, end - b);
        int sv = 0; float ev = 0.f;
        if (lane < cnt) { sv = perm_src[b + lane]; ev = perm_e[b + lane]; }
        for (int t = 0; t < cnt; ++t) {
            int s = __shfl(sv, t, 64);
            float e = __shfl(ev, t, 64);
            acc = fmaf(e, a[(size_t)s * 64 + lane], acc);
        }
    }
    h[(size_t)node * 64 + lane] = fmaxf(acc, 0.f);
}

// ---------------- pooling + MLP ----------------

__global__ __launch_bounds__(256) void pool_kernel(const float* __restrict__ h,
                                                   const int* __restrict__ batch,
                                                   float* __restrict__ gx) {
    __shared__ int lohi[2];
    __shared__ float red[4][64];
    int g = blockIdx.x;
    if (threadIdx.x < 2) {
        int target = g + threadIdx.x;
        int lo = 0, hi = NNODES;
        while (lo < hi) { int m = (lo + hi) >> 1; if (batch[m] < target) lo = m + 1; else hi = m; }
        lohi[threadIdx.x] = lo;
    }
    __syncthreads();
    int lo = lohi[0], hi = lohi[1];
    int lane = threadIdx.x & 63, w = threadIdx.x >> 6;
    float sum = 0.f;
    for (int n = lo + w; n < hi; n += 4) sum += h[(size_t)n * 64 + lane];
    red[w][lane] = sum;
    __syncthreads();
    if (w == 0) {
        float tot = red[0][lane] + red[1][lane] + red[2][lane] + red[3][lane];
        int cnt = hi - lo;
        gx[g * 64 + lane] = tot / (float)max(cnt, 1);
    }
}

__global__ __launch_bounds__(64) void mlp_kernel(const float* __restrict__ gx,
                                                 const float* __restrict__ Wl1,
                                                 const float* __restrict__ bl1,
                                                 const float* __restrict__ Wl2,
                                                 const float* __restrict__ bl2,
                                                 float* __restrict__ out) {
    __shared__ float gxl[64];
    __shared__ float hid[32];
    int g = blockIdx.x, t = threadIdx.x;
    gxl[t] = gx[g * 64 + t];
    __syncthreads();
    if (t < 32) {
        float s = bl1[t];
        for (int k = 0; k < 64; ++k) s = fmaf(gxl[k], Wl1[k * 32 + t], s);
        hid[t] = fmaxf(s, 0.f);
    }
    __syncthreads();
    if (t < 3) {
        float s = bl2[t];
        for (int k = 0; k < 32; ++k) s = fmaf(hid[k], Wl2[k * 3 + t], s);
        out[g * 3 + t] = s;
    }
}

// ---------------- launch ----------------

extern "C" void kernel_launch(void* const* d_in, const int* in_sizes, int n_in,
                              void* d_out, int out_size, void* d_ws, size_t ws_size,
                              hipStream_t stream) {
    const float* x    = (const float*)d_in[0];
    const int*   ei   = (const int*)d_in[1];
    const float* ea   = (const float*)d_in[2];
    const int*   bat  = (const int*)d_in[3];
    const float* Wemb = (const float*)d_in[4];
    const float* bemb = (const float*)d_in[5];
    const float* W1   = (const float*)d_in[6];
    const float* b1   = (const float*)d_in[7];
    const float* W2   = (const float*)d_in[8];
    const float* W3   = (const float*)d_in[9];
    const float* b3   = (const float*)d_in[10];
    const float* Wl1  = (const float*)d_in[11];
    const float* bl1  = (const float*)d_in[12];
    const float* Wl2  = (const float*)d_in[13];
    const float* bl2  = (const float*)d_in[14];
    float* out = (float*)d_out;

    char* ws = (char*)d_ws;
    float* h        = (float*)(ws + 0);          // 25,600,000 B
    float* a        = (float*)(ws + 25600000);   // 25,600,000 B
    int*   perm_src = (int*)  (ws + 51200000);   //  6,400,000 B
    float* perm_e   = (float*)(ws + 57600000);   //  6,400,000 B
    int*   row_ptr  = (int*)  (ws + 64000000);   //    400,128 B (N+1)
    int*   cursor   = (int*)  (ws + 64400128);   //    400,000 B
    float* wdeg     = (float*)(ws + 64800128);   //    400,000 B
    int*   deg      = (int*)  (ws + 65200128);   //    400,000 B
    int*   bsums    = (int*)  (ws + 65600128);   //      1,024 B
    float* gx       = (float*)(ws + 65601152);   //    131,072 B  -> end ~65.73 MB

    zero_kernel<<<(NNODES + 255) / 256, 256, 0, stream>>>(deg, wdeg);
    hist_kernel<<<NEDGES / 256, 256, 0, stream>>>(ei, ea, deg, wdeg);
    scan_blocks_kernel<<<NBLK_SCAN, 256, 0, stream>>>(deg, row_ptr, bsums);
    scan_sums_kernel<<<1, 128, 0, stream>>>(bsums);
    add_offsets_kernel<<<(NNODES + 255) / 256, 256, 0, stream>>>(row_ptr, bsums, cursor);
    scatter_kernel<<<NEDGES / 256, 256, 0, stream>>>(ei, ea, cursor, perm_src, perm_e);

    embed_kernel<<<NNODES * 64 / 256, 256, 0, stream>>>(x, Wemb, bemb, h);
    for (int l = 0; l < NLAYER; ++l) {
        gemm3_kernel<<<(NNODES + 31) / 32, 256, 0, stream>>>(
            h, wdeg, W1 + l * 4096, b1 + l * 64, W2 + l * 4096, W3 + l * 4096, b3 + l * 64, a);
        edge_agg_kernel<<<(NNODES + 3) / 4, 256, 0, stream>>>(a, h, row_ptr, perm_src, perm_e);
    }
    pool_kernel<<<NGRAPH, 256, 0, stream>>>(h, bat, gx);
    mlp_kernel<<<NGRAPH, 64, 0, stream>>>(gx, Wl1, bl1, Wl2, bl2, out);
}